// Round 10
// baseline (113.032 us; speedup 1.0000x reference)
//
#include <hip/hip_runtime.h>
#include <hip/hip_bf16.h>

#define NB 8192   // B
#define ND 128    // D
#define N2 16384  // 2B

#define CPB 512               // columns per strip-block
#define CTILE 64              // columns staged per LDS tile
#define NT (CPB / CTILE)      // 8 tiles per block

typedef __attribute__((ext_vector_type(8))) short short8;
typedef __attribute__((ext_vector_type(4))) float f32x4;

// sqrt((1/T) * log2(e)) with T=0.5 : sqrt(2.8853900817779268)
static constexpr float SQRT_C_VAL = 1.69864368f;

__device__ inline unsigned short f2bf(float f) {
    __hip_bfloat16 h = __float2bfloat16(f);
    return __builtin_bit_cast(unsigned short, h);
}

// ---------------- normalize + positive-pair dot ----------------
__global__ __launch_bounds__(256) void nrm_kernel(const float* __restrict__ zi,
                                                  const float* __restrict__ zj,
                                                  unsigned int* __restrict__ reps_u32,
                                                  float* __restrict__ pos) {
    const int pair = (int)((blockIdx.x * 256 + threadIdx.x) >> 6);
    const int lane = threadIdx.x & 63;
    const float2 vi = *reinterpret_cast<const float2*>(zi + pair * ND + lane * 2);
    const float2 vj = *reinterpret_cast<const float2*>(zj + pair * ND + lane * 2);
    float ssi = vi.x * vi.x + vi.y * vi.y;
    float ssj = vj.x * vj.x + vj.y * vj.y;
#pragma unroll
    for (int m = 1; m < 64; m <<= 1) {
        ssi += __shfl_xor(ssi, m);
        ssj += __shfl_xor(ssj, m);
    }
    float ni = fmaxf(sqrtf(ssi), 1e-12f);
    float nj = fmaxf(sqrtf(ssj), 1e-12f);
    const float ii = 1.0f / ni, ij = 1.0f / nj;
    const float uix = vi.x * ii, uiy = vi.y * ii;
    const float ujx = vj.x * ij, ujy = vj.y * ij;
    float d = uix * ujx + uiy * ujy;
#pragma unroll
    for (int m = 1; m < 64; m <<= 1) d += __shfl_xor(d, m);
    if (lane == 0) pos[pair] = d;
    const unsigned int pi =
        (unsigned int)f2bf(uix * SQRT_C_VAL) | ((unsigned int)f2bf(uiy * SQRT_C_VAL) << 16);
    const unsigned int pj =
        (unsigned int)f2bf(ujx * SQRT_C_VAL) | ((unsigned int)f2bf(ujy * SQRT_C_VAL) << 16);
    reps_u32[pair * 64 + lane] = pi;
    reps_u32[(NB + pair) * 64 + lane] = pj;
}

// ---------------- fused sim-GEMM + sum(exp2), upper-triangle strips ----------------
__device__ inline void gload_lds16(const void* g, void* l) {
    __builtin_amdgcn_global_load_lds(
        (const __attribute__((address_space(1))) void*)g,
        (__attribute__((address_space(3))) void*)l, 16, 0, 0);
}

__global__ __launch_bounds__(512, 3) void sim_kernel(const char* __restrict__ reps,
                                                     float* __restrict__ ssum) {
    const int a = blockIdx.x;   // row-block (256 rows)
    const int s = blockIdx.y;   // col-strip (512 cols)
    if (a > 2 * s + 1) return;  // strictly lower-triangle strip: nothing to do

    __shared__ __align__(16) char lds[2][CTILE * 256];  // 2 x 16 KiB K-panel tiles
    __shared__ float cs_lds[CPB];                       // column-sum accumulator (2 KiB)

    const int tid = threadIdx.x;
    const int lane = tid & 63;
    const int wid = tid >> 6;       // 0..7
    const int l15 = lane & 15;
    const int l4 = lane >> 4;
    const int rb = a * 256;           // 256 rows per block
    const int cb = s * CPB;           // 512-col strip
    const int qb = rb + wid * 32;     // this wave's 32 rows

    if (tid < CPB) cs_lds[tid] = 0.f;

    // Q fragments resident: 2 row-groups x 4 k-chunks (32 VGPRs)
    short8 qf[2][4];
#pragma unroll
    for (int g = 0; g < 2; ++g)
#pragma unroll
        for (int kk = 0; kk < 4; ++kk)
            qf[g][kk] = *reinterpret_cast<const short8*>(
                reps + (size_t)(qb + g * 16 + l15) * 256 + l4 * 16 + kk * 64);

    float sacc[2][4];
#pragma unroll
    for (int g = 0; g < 2; ++g)
#pragma unroll
        for (int r = 0; r < 4; ++r) sacc[g][r] = 0.f;

    auto stage = [&](int buf, int t) {
        const int colbase = cb + t * CTILE;
#pragma unroll
        for (int q = 0; q < 2; ++q) {
            const int slot = q * 512 + tid;  // 16B slot 0..1023
            const int r = slot >> 4, c = slot & 15;
            // pre-swizzled global source (rule #21): LDS linear, slot (r,c) <- chunk (r, c^(r&15))
            const char* src = reps + (size_t)(colbase + r) * 256 + ((c ^ (r & 15)) * 16);
            char* dst = &lds[buf][(q * 512 + wid * 64) * 16];  // wave-uniform base
            gload_lds16(src, dst);
        }
    };

    auto compute = [&](int buf, int tc) {
        if (tc + CTILE <= qb) return;           // fully below diagonal for this wave
        const bool upper = (tc >= qb + 32);     // strictly upper: no masking needed
#pragma unroll
        for (int cg = 0; cg < 4; ++cg) {
            const int kr = cg * 16 + l15;
            const char* lb = &lds[buf][kr * 256];
            short8 kf[4];
#pragma unroll
            for (int kk = 0; kk < 4; ++kk)
                kf[kk] = *reinterpret_cast<const short8*>(lb + (((kk * 4 + l4) ^ (kr & 15)) * 16));
            float csum = 0.f;
#pragma unroll
            for (int g = 0; g < 2; ++g) {
                f32x4 acc = {0.f, 0.f, 0.f, 0.f};
#pragma unroll
                for (int kk = 0; kk < 4; ++kk)
                    acc = __builtin_amdgcn_mfma_f32_16x16x32_bf16(qf[g][kk], kf[kk], acc, 0, 0, 0);
                if (upper) {
#pragma unroll
                    for (int r = 0; r < 4; ++r) {
                        const float e = __builtin_amdgcn_exp2f(acc[r]);
                        sacc[g][r] += e;
                        csum += e;
                    }
                } else {
                    const int col = tc + cg * 16 + l15;
                    const int row0 = qb + g * 16 + l4 * 4;
#pragma unroll
                    for (int r = 0; r < 4; ++r) {
                        const float e = __builtin_amdgcn_exp2f(acc[r]);
                        const float em = (col > row0 + r) ? e : 0.f;  // upper-strict mask
                        sacc[g][r] += em;
                        csum += em;
                    }
                }
            }
            // column partial sums: reduce over the 4 row-groups (l4), then LDS atomic
            csum += __shfl_xor(csum, 16);
            csum += __shfl_xor(csum, 32);
            if (lane < 16) atomicAdd(&cs_lds[tc - cb + cg * 16 + lane], csum);
        }
    };

    stage(0, 0);
    __syncthreads();
    int cur = 0;
    for (int t = 0; t < NT; ++t) {
        if (t + 1 < NT) stage(cur ^ 1, t + 1);
        compute(cur, cb + t * CTILE);
        __syncthreads();
        cur ^= 1;
    }

    // row sums: reduce across the 16 column-lanes, then one atomic per row
#pragma unroll
    for (int g = 0; g < 2; ++g)
#pragma unroll
        for (int r = 0; r < 4; ++r) {
#pragma unroll
            for (int m = 1; m < 16; m <<= 1) sacc[g][r] += __shfl_xor(sacc[g][r], m);
        }
    if (l15 == 0) {
#pragma unroll
        for (int g = 0; g < 2; ++g)
#pragma unroll
            for (int r = 0; r < 4; ++r)
                atomicAdd(&ssum[qb + g * 16 + l4 * 4 + r], sacc[g][r]);
    }

    // column sums: one flush per block
    if (tid < CPB) {
        const float v = cs_lds[tid];
        if (v != 0.f) atomicAdd(&ssum[cb + tid], v);
    }
}

// ---------------- finalize: loss = mean(ln(ssum) - 2*pos) ----------------
__global__ __launch_bounds__(1024) void fin_kernel(const float* __restrict__ ssum,
                                                   const float* __restrict__ pos,
                                                   float* __restrict__ out) {
    const int tid = threadIdx.x;
    float acc = 0.f;
    for (int r = tid; r < N2; r += 1024) {
        const int p = (r < NB) ? r : r - NB;
        acc += logf(ssum[r]) - 2.0f * pos[p];
    }
#pragma unroll
    for (int m = 1; m < 64; m <<= 1) acc += __shfl_xor(acc, m);
    __shared__ float red[16];
    const int wid = tid >> 6, lane = tid & 63;
    if (lane == 0) red[wid] = acc;
    __syncthreads();
    if (wid == 0) {
        float v = (lane < 16) ? red[lane] : 0.f;
#pragma unroll
        for (int m = 1; m < 16; m <<= 1) v += __shfl_xor(v, m);
        if (lane == 0) out[0] = v / (float)N2;
    }
}

extern "C" void kernel_launch(void* const* d_in, const int* in_sizes, int n_in,
                              void* d_out, int out_size, void* d_ws, size_t ws_size,
                              hipStream_t stream) {
    const float* zi = (const float*)d_in[0];
    const float* zj = (const float*)d_in[1];
    float* out = (float*)d_out;
    char* ws = (char*)d_ws;

    char* reps = ws;                                       // 16384*128*2 = 4 MiB bf16
    float* pos = (float*)(ws + (size_t)N2 * ND * 2);       // 8192 f32
    float* ssum = pos + NB;                                // 16384 f32

    (void)hipMemsetAsync(ssum, 0, N2 * sizeof(float), stream);
    nrm_kernel<<<NB / 4, 256, 0, stream>>>(zi, zj, (unsigned int*)reps, pos);
    dim3 grid(64, 32);
    sim_kernel<<<grid, 512, 0, stream>>>(reps, ssum);
    fin_kernel<<<1, 1024, 0, stream>>>(ssum, pos, out);
}

// Round 11
// 84.952 us; speedup vs baseline: 1.3305x; 1.3305x over previous
//
#include <hip/hip_runtime.h>
#include <hip/hip_bf16.h>

#define NB 8192   // B
#define ND 128    // D
#define N2 16384  // 2B

#define CPB 1024              // columns per block (16-way column split)
#define CTILE 64              // columns staged per LDS tile
#define NT (CPB / CTILE)      // 16 tiles per block

typedef __attribute__((ext_vector_type(8))) short short8;
typedef __attribute__((ext_vector_type(4))) float f32x4;

// sqrt((1/T) * log2(e)) with T=0.5 : sqrt(2.8853900817779268)
static constexpr float SQRT_C_VAL = 1.69864368f;

__device__ inline unsigned short f2bf(float f) {
    __hip_bfloat16 h = __float2bfloat16(f);
    return __builtin_bit_cast(unsigned short, h);
}

// ---------------- normalize + positive-pair dot (+ ssum zero-init) ----------------
__global__ __launch_bounds__(256) void nrm_kernel(const float* __restrict__ zi,
                                                  const float* __restrict__ zj,
                                                  unsigned int* __restrict__ reps_u32,
                                                  float* __restrict__ pos,
                                                  float* __restrict__ ssum) {
    const int gtid = blockIdx.x * 256 + threadIdx.x;
    if (gtid < N2) ssum[gtid] = 0.f;  // replaces the hipMemsetAsync dispatch
    const int pair = gtid >> 6;
    const int lane = threadIdx.x & 63;
    const float2 vi = *reinterpret_cast<const float2*>(zi + pair * ND + lane * 2);
    const float2 vj = *reinterpret_cast<const float2*>(zj + pair * ND + lane * 2);
    float ssi = vi.x * vi.x + vi.y * vi.y;
    float ssj = vj.x * vj.x + vj.y * vj.y;
#pragma unroll
    for (int m = 1; m < 64; m <<= 1) {
        ssi += __shfl_xor(ssi, m);
        ssj += __shfl_xor(ssj, m);
    }
    float ni = fmaxf(sqrtf(ssi), 1e-12f);
    float nj = fmaxf(sqrtf(ssj), 1e-12f);
    const float ii = 1.0f / ni, ij = 1.0f / nj;
    const float uix = vi.x * ii, uiy = vi.y * ii;
    const float ujx = vj.x * ij, ujy = vj.y * ij;
    float d = uix * ujx + uiy * ujy;
#pragma unroll
    for (int m = 1; m < 64; m <<= 1) d += __shfl_xor(d, m);
    if (lane == 0) pos[pair] = d;
    const unsigned int pi =
        (unsigned int)f2bf(uix * SQRT_C_VAL) | ((unsigned int)f2bf(uiy * SQRT_C_VAL) << 16);
    const unsigned int pj =
        (unsigned int)f2bf(ujx * SQRT_C_VAL) | ((unsigned int)f2bf(ujy * SQRT_C_VAL) << 16);
    reps_u32[pair * 64 + lane] = pi;
    reps_u32[(NB + pair) * 64 + lane] = pj;
}

// ---------------- fused sim-GEMM + sum(exp2), phase-split schedule ----------------
__device__ inline void gload_lds16(const void* g, void* l) {
    __builtin_amdgcn_global_load_lds(
        (const __attribute__((address_space(1))) void*)g,
        (__attribute__((address_space(3))) void*)l, 16, 0, 0);
}

__global__ __launch_bounds__(512, 3) void sim_kernel(const char* __restrict__ reps,
                                                     float* __restrict__ ssum) {
    __shared__ __align__(16) char lds[2][CTILE * 256];  // 2 x 16 KiB
    const int tid = threadIdx.x;
    const int lane = tid & 63;
    const int wid = tid >> 6;       // 0..7
    const int l15 = lane & 15;
    const int l4 = lane >> 4;
    const int rb = blockIdx.x * 256;  // 256 rows per block
    const int cb = blockIdx.y * CPB;  // column split
    const int qb = rb + wid * 32;     // this wave's 32 rows

    // Q fragments resident: 2 row-groups x 4 k-chunks (32 VGPRs)
    short8 qf[2][4];
#pragma unroll
    for (int g = 0; g < 2; ++g)
#pragma unroll
        for (int kk = 0; kk < 4; ++kk)
            qf[g][kk] = *reinterpret_cast<const short8*>(
                reps + (size_t)(qb + g * 16 + l15) * 256 + l4 * 16 + kk * 64);

    float sacc[2][4];
#pragma unroll
    for (int g = 0; g < 2; ++g)
#pragma unroll
        for (int r = 0; r < 4; ++r) sacc[g][r] = 0.f;

    auto stage = [&](int buf, int t) {
        const int colbase = cb + t * CTILE;
#pragma unroll
        for (int q = 0; q < 2; ++q) {
            const int s = q * 512 + tid;  // 16B slot 0..1023
            const int r = s >> 4, c = s & 15;
            // pre-swizzled global source (rule #21): LDS linear, slot (r,c) <- chunk (r, c^(r&15))
            const char* src = reps + (size_t)(colbase + r) * 256 + ((c ^ (r & 15)) * 16);
            char* dst = &lds[buf][(q * 512 + wid * 64) * 16];  // wave-uniform base
            gload_lds16(src, dst);
        }
    };

    stage(0, 0);
    __syncthreads();
    int cur = 0;
    for (int t = 0; t < NT; ++t) {
        const int tc = cb + t * CTILE;
        const bool dg = ((unsigned)(qb - tc) < 64u);  // wave rows overlap this 64-col tile
#pragma unroll
        for (int cg = 0; cg < 4; ++cg) {
            // --- phase cg: ds_read || (stage in phase 0) -> barrier -> MFMA -> epilogue -> barrier
            const int kr = cg * 16 + l15;
            const char* lb = &lds[cur][kr * 256];
            short8 kf[4];
#pragma unroll
            for (int kk = 0; kk < 4; ++kk)
                kf[kk] = *reinterpret_cast<const short8*>(lb + (((kk * 4 + l4) ^ (kr & 15)) * 16));
            if (cg == 0 && t + 1 < NT) stage(cur ^ 1, t + 1);
            __builtin_amdgcn_s_barrier();
            asm volatile("s_waitcnt lgkmcnt(0)" ::: "memory");
            __builtin_amdgcn_sched_barrier(0);  // rule #18: fence MFMA behind the lgkmcnt
            __builtin_amdgcn_s_setprio(1);
            f32x4 acc0 = {0.f, 0.f, 0.f, 0.f};
            f32x4 acc1 = {0.f, 0.f, 0.f, 0.f};
#pragma unroll
            for (int kk = 0; kk < 4; ++kk)
                acc0 = __builtin_amdgcn_mfma_f32_16x16x32_bf16(qf[0][kk], kf[kk], acc0, 0, 0, 0);
#pragma unroll
            for (int kk = 0; kk < 4; ++kk)
                acc1 = __builtin_amdgcn_mfma_f32_16x16x32_bf16(qf[1][kk], kf[kk], acc1, 0, 0, 0);
            __builtin_amdgcn_s_setprio(0);
            // epilogue (VALU/trans) — overlaps other waves' MFMA phases
            if (!dg) {
#pragma unroll
                for (int r = 0; r < 4; ++r) {
                    sacc[0][r] += __builtin_amdgcn_exp2f(acc0[r]);
                    sacc[1][r] += __builtin_amdgcn_exp2f(acc1[r]);
                }
            } else {
                const int col = tc + cg * 16 + l15;
#pragma unroll
                for (int r = 0; r < 4; ++r) {
                    const float e0 = __builtin_amdgcn_exp2f(acc0[r]);
                    const float e1 = __builtin_amdgcn_exp2f(acc1[r]);
                    sacc[0][r] += (qb + l4 * 4 + r == col) ? 0.f : e0;
                    sacc[1][r] += (qb + 16 + l4 * 4 + r == col) ? 0.f : e1;
                }
            }
            __builtin_amdgcn_s_barrier();
        }
        // drain my 2 stage loads (issued 4 phases ago — nearly free), then release buffers
        asm volatile("s_waitcnt vmcnt(0)" ::: "memory");
        __builtin_amdgcn_s_barrier();
        cur ^= 1;
    }

    // reduce across the 16 column-lanes, then one atomic per row
#pragma unroll
    for (int g = 0; g < 2; ++g)
#pragma unroll
        for (int r = 0; r < 4; ++r) {
#pragma unroll
            for (int m = 1; m < 16; m <<= 1) sacc[g][r] += __shfl_xor(sacc[g][r], m);
        }
    if (l15 == 0) {
#pragma unroll
        for (int g = 0; g < 2; ++g)
#pragma unroll
            for (int r = 0; r < 4; ++r)
                atomicAdd(&ssum[qb + g * 16 + l4 * 4 + r], sacc[g][r]);
    }
}

// ---------------- finalize: loss = mean(ln(ssum) - 2*pos) ----------------
__global__ __launch_bounds__(1024) void fin_kernel(const float* __restrict__ ssum,
                                                   const float* __restrict__ pos,
                                                   float* __restrict__ out) {
    const int tid = threadIdx.x;
    float acc = 0.f;
    for (int r = tid; r < N2; r += 1024) {
        const int p = (r < NB) ? r : r - NB;
        acc += logf(ssum[r]) - 2.0f * pos[p];
    }
#pragma unroll
    for (int m = 1; m < 64; m <<= 1) acc += __shfl_xor(acc, m);
    __shared__ float red[16];
    const int wid = tid >> 6, lane = tid & 63;
    if (lane == 0) red[wid] = acc;
    __syncthreads();
    if (wid == 0) {
        float v = (lane < 16) ? red[lane] : 0.f;
#pragma unroll
        for (int m = 1; m < 16; m <<= 1) v += __shfl_xor(v, m);
        if (lane == 0) out[0] = v / (float)N2;
    }
}

extern "C" void kernel_launch(void* const* d_in, const int* in_sizes, int n_in,
                              void* d_out, int out_size, void* d_ws, size_t ws_size,
                              hipStream_t stream) {
    const float* zi = (const float*)d_in[0];
    const float* zj = (const float*)d_in[1];
    float* out = (float*)d_out;
    char* ws = (char*)d_ws;

    char* reps = ws;                                       // 16384*128*2 = 4 MiB bf16
    float* pos = (float*)(ws + (size_t)N2 * ND * 2);       // 8192 f32
    float* ssum = pos + NB;                                // 16384 f32

    nrm_kernel<<<NB / 4, 256, 0, stream>>>(zi, zj, (unsigned int*)reps, pos, ssum);
    dim3 grid(N2 / 256, N2 / CPB);
    sim_kernel<<<grid, 512, 0, stream>>>(reps, ssum);
    fin_kernel<<<1, 1024, 0, stream>>>(ssum, pos, out);
}

// Round 12
// 67.525 us; speedup vs baseline: 1.6739x; 1.2581x over previous
//
#include <hip/hip_runtime.h>
#include <hip/hip_bf16.h>

#define NB 8192   // B
#define ND 128    // D
#define N2 16384  // 2B

#define CPB 1024              // columns per block (16-way column split)
#define CTILE 64              // columns staged per LDS tile
#define NT (CPB / CTILE)      // 16 tiles per block

typedef __attribute__((ext_vector_type(4))) float f32x4;
typedef __attribute__((ext_vector_type(8))) int v8i;

// sqrt((1/T) * log2(e)) with T=0.5 : sqrt(2.8853900817779268)
static constexpr float SQRT_C_VAL = 1.69864368f;

// ---------------- normalize + positive-pair dot + fp8 quantize (+ ssum zero) ----------------
__global__ __launch_bounds__(256) void nrm_kernel(const float* __restrict__ zi,
                                                  const float* __restrict__ zj,
                                                  unsigned short* __restrict__ reps8_u16,
                                                  float* __restrict__ pos,
                                                  float* __restrict__ ssum) {
    const int gtid = blockIdx.x * 256 + threadIdx.x;
    if (gtid < N2) ssum[gtid] = 0.f;  // replaces the hipMemsetAsync dispatch
    const int pair = gtid >> 6;
    const int lane = threadIdx.x & 63;
    const float2 vi = *reinterpret_cast<const float2*>(zi + pair * ND + lane * 2);
    const float2 vj = *reinterpret_cast<const float2*>(zj + pair * ND + lane * 2);
    float ssi = vi.x * vi.x + vi.y * vi.y;
    float ssj = vj.x * vj.x + vj.y * vj.y;
#pragma unroll
    for (int m = 1; m < 64; m <<= 1) {
        ssi += __shfl_xor(ssi, m);
        ssj += __shfl_xor(ssj, m);
    }
    float ni = fmaxf(sqrtf(ssi), 1e-12f);
    float nj = fmaxf(sqrtf(ssj), 1e-12f);
    const float ii = 1.0f / ni, ij = 1.0f / nj;
    const float uix = vi.x * ii, uiy = vi.y * ii;
    const float ujx = vj.x * ij, ujy = vj.y * ij;
    float d = uix * ujx + uiy * ujy;
#pragma unroll
    for (int m = 1; m < 64; m <<= 1) d += __shfl_xor(d, m);
    if (lane == 0) pos[pair] = d;
    // fp8 e4m3 (OCP on gfx950), pre-scaled by sqrt(C) so MFMA output = sim * C = exp2 arg
    const int pki = __builtin_amdgcn_cvt_pk_fp8_f32(uix * SQRT_C_VAL, uiy * SQRT_C_VAL, 0, false);
    const int pkj = __builtin_amdgcn_cvt_pk_fp8_f32(ujx * SQRT_C_VAL, ujy * SQRT_C_VAL, 0, false);
    reps8_u16[pair * 64 + lane] = (unsigned short)(pki & 0xFFFF);
    reps8_u16[(NB + pair) * 64 + lane] = (unsigned short)(pkj & 0xFFFF);
}

// ---------------- fused sim-GEMM (MX-fp8 K=128) + sum(exp2) ----------------
__device__ inline void gload_lds16(const void* g, void* l) {
    __builtin_amdgcn_global_load_lds(
        (const __attribute__((address_space(1))) void*)g,
        (__attribute__((address_space(3))) void*)l, 16, 0, 0);
}

__global__ __launch_bounds__(512, 3) void sim_kernel(const char* __restrict__ reps8,
                                                     float* __restrict__ ssum) {
    __shared__ __align__(16) char lds[2][CTILE * 128];  // 2 x 8 KiB fp8 K-panel tiles
    const int tid = threadIdx.x;
    const int lane = tid & 63;
    const int wid = tid >> 6;       // 0..7
    const int l15 = lane & 15;
    const int l4 = lane >> 4;
    const int rb = blockIdx.x * 256;  // 256 rows per block (8 waves x 32)
    const int cb = blockIdx.y * CPB;  // column split
    const int qb = rb + wid * 32;     // this wave's 32 rows

    // Q fragments: per lane row (qb+g*16+l15), contiguous 32 fp8 at k = 32*l4
    v8i qf[2];
#pragma unroll
    for (int g = 0; g < 2; ++g)
        qf[g] = *reinterpret_cast<const v8i*>(
            reps8 + (size_t)(qb + g * 16 + l15) * 128 + l4 * 32);

    f32x4 sacc0 = {0.f, 0.f, 0.f, 0.f};
    f32x4 sacc1 = {0.f, 0.f, 0.f, 0.f};

    auto stage = [&](int buf, int t) {
        const int colbase = cb + t * CTILE;
        // 512 slots of 16B, one per thread. row r = col, 8 chunks of 16B per row.
        const int r = tid >> 3, c2 = tid & 7;
        // inverse-swizzled source (rule #21): LDS linear; 32B-granule XOR with (r&3)
        const char* src = reps8 + (size_t)(colbase + r) * 128 +
                          (((c2 >> 1) ^ (r & 3)) * 32 + (c2 & 1) * 16);
        char* dst = &lds[buf][wid * 1024];  // wave-uniform base
        gload_lds16(src, dst);
    };

    stage(0, 0);
    __syncthreads();
    int cur = 0;
    for (int t = 0; t < NT; ++t) {
        const int tc = cb + t * CTILE;
        if (t + 1 < NT) stage(cur ^ 1, t + 1);
        const bool dg = ((unsigned)(qb - tc) < 64u);  // wave rows overlap this 64-col tile
#pragma unroll
        for (int cg = 0; cg < 4; ++cg) {
            // K fragment: col = tc+cg*16+l15, contiguous 32B at swizzled 32B-chunk (l4^(col&3))
            const v8i kf = *reinterpret_cast<const v8i*>(
                &lds[cur][(cg * 16 + l15) * 128 + ((l4 ^ (l15 & 3)) * 32)]);
            const f32x4 z4 = {0.f, 0.f, 0.f, 0.f};
            f32x4 acc0 = __builtin_amdgcn_mfma_scale_f32_16x16x128_f8f6f4(
                qf[0], kf, z4, 0, 0, 0, 0x7F7F7F7F, 0, 0x7F7F7F7F);
            f32x4 acc1 = __builtin_amdgcn_mfma_scale_f32_16x16x128_f8f6f4(
                qf[1], kf, z4, 0, 0, 0, 0x7F7F7F7F, 0, 0x7F7F7F7F);
            f32x4 e0, e1;
#pragma unroll
            for (int r = 0; r < 4; ++r) {
                e0[r] = __builtin_amdgcn_exp2f(acc0[r]);
                e1[r] = __builtin_amdgcn_exp2f(acc1[r]);
            }
            if (dg) {
                const int col = tc + cg * 16 + l15;
#pragma unroll
                for (int r = 0; r < 4; ++r) {
                    if (qb + l4 * 4 + r == col) e0[r] = 0.f;
                    if (qb + 16 + l4 * 4 + r == col) e1[r] = 0.f;
                }
            }
            sacc0 += e0;
            sacc1 += e1;
        }
        __syncthreads();
        cur ^= 1;
    }

    // reduce across the 16 column-lanes, then one atomic per row
#pragma unroll
    for (int r = 0; r < 4; ++r) {
#pragma unroll
        for (int m = 1; m < 16; m <<= 1) {
            sacc0[r] += __shfl_xor(sacc0[r], m);
            sacc1[r] += __shfl_xor(sacc1[r], m);
        }
    }
    if (l15 == 0) {
#pragma unroll
        for (int r = 0; r < 4; ++r) {
            atomicAdd(&ssum[qb + l4 * 4 + r], sacc0[r]);
            atomicAdd(&ssum[qb + 16 + l4 * 4 + r], sacc1[r]);
        }
    }
}

// ---------------- finalize: loss = mean(ln(ssum) - 2*pos) ----------------
__global__ __launch_bounds__(1024) void fin_kernel(const float* __restrict__ ssum,
                                                   const float* __restrict__ pos,
                                                   float* __restrict__ out) {
    const int tid = threadIdx.x;
    float acc = 0.f;
    for (int r = tid; r < N2; r += 1024) {
        const int p = (r < NB) ? r : r - NB;
        acc += logf(ssum[r]) - 2.0f * pos[p];
    }
#pragma unroll
    for (int m = 1; m < 64; m <<= 1) acc += __shfl_xor(acc, m);
    __shared__ float red[16];
    const int wid = tid >> 6, lane = tid & 63;
    if (lane == 0) red[wid] = acc;
    __syncthreads();
    if (wid == 0) {
        float v = (lane < 16) ? red[lane] : 0.f;
#pragma unroll
        for (int m = 1; m < 16; m <<= 1) v += __shfl_xor(v, m);
        if (lane == 0) out[0] = v / (float)N2;
    }
}

extern "C" void kernel_launch(void* const* d_in, const int* in_sizes, int n_in,
                              void* d_out, int out_size, void* d_ws, size_t ws_size,
                              hipStream_t stream) {
    const float* zi = (const float*)d_in[0];
    const float* zj = (const float*)d_in[1];
    float* out = (float*)d_out;
    char* ws = (char*)d_ws;

    char* reps8 = ws;                                      // 16384*128 = 2 MiB fp8
    float* pos = (float*)(ws + (size_t)N2 * ND);           // 8192 f32
    float* ssum = pos + NB;                                // 16384 f32

    nrm_kernel<<<NB / 4, 256, 0, stream>>>(zi, zj, (unsigned short*)reps8, pos, ssum);
    dim3 grid(N2 / 256, N2 / CPB);
    sim_kernel<<<grid, 512, 0, stream>>>(reps8, ssum);
    fin_kernel<<<1, 1024, 0, stream>>>(ssum, pos, out);
}